// Round 1
// 220.928 us; speedup vs baseline: 1.0770x; 1.0770x over previous
//
#include <hip/hip_runtime.h>

// Problem constants
#define N_     8
#define C_     16
#define T_     300
#define F_     257
#define TF_    (T_*F_)        // 77100
#define CTF_   (C_*TF_)       // 1233600
#define N2CTF_ (2*CTF_)       // per-batch stride in floats (re+im planes)

// K1 tiling
#define FT_    32             // f-tile width
#define NFT_   9              // ceil(257/32)
#define TS_    5              // t's staged per LDS stage (== waves/block)
#define SROW_  34             // 32 y rows (c*2+plane) + 2 x rows (re,im)
#define SSTG_  (SROW_*32)     // floats per staged t = 1088
#define SBUF_  (TS_*SSTG_)    // floats per buffer = 5440 (21.75 KB); x2 = 43.5 KB
#define NTILE_ 10             // lower-triangle 4x4 tiles of the 16x16 Hermitian phi
#define PHIC_  (NTILE_*16)    // 160 float2 stored per (tc,n,f)

#define MREC_  272            // packed M record: 256 matrix + 16 rhs (float2)

#define LOADC  7.0710678118654755e-04f   // 0.001/sqrt(2)

typedef float v2f __attribute__((ext_vector_type(2)));

__device__ __forceinline__ float2 cmul(float2 a, float2 b) {
  return make_float2(a.x*b.x - a.y*b.y, a.x*b.y + a.y*b.x);
}
__device__ __forceinline__ float2 cmulc(float2 a, float2 b) { // a * conj(b)
  return make_float2(a.x*b.x + a.y*b.y, a.y*b.x - a.x*b.y);
}
__device__ __forceinline__ float2 cdiv(float2 a, float2 b) {
  float inv = 1.0f / (b.x*b.x + b.y*b.y);
  return make_float2((a.x*b.x + a.y*b.y)*inv, (a.y*b.x - a.x*b.y)*inv);
}
__device__ __forceinline__ float2 cadd(float2 a, float2 b){ return make_float2(a.x+b.x, a.y+b.y); }
__device__ __forceinline__ float2 csub(float2 a, float2 b){ return make_float2(a.x-b.x, a.y-b.y); }

// Async global->LDS DMA, 4 B per lane. LDS dest is wave-uniform base + lane*4;
// global src is per-lane.
__device__ __forceinline__ void gload4(const float* g, float* l) {
  __builtin_amdgcn_global_load_lds(
      (const __attribute__((address_space(1))) unsigned int*)g,
      (__attribute__((address_space(3))) unsigned int*)l, 4, 0, 0);
}

// ---------------------------------------------------------------------------
// K1 v6: Hermitian partial covariance + cross sums.
// grid (NFT_, TCP, N_), block 320 = 32 f-lanes x 10 lower-triangle groups.
// Staging via global_load_lds into a TRUE double buffer (planar re/im rows of
// stride 32 so the DMA's lane*4 contiguous dest matches the layout; x = rows
// 32/33). One barrier per stage; next-stage DMA is issued right after the
// barrier and drains at the NEXT barrier, so HBM latency hides under a full
// compute phase. TCP=10 -> 720 blocks = all-resident at 3 blocks/CU (no tail).
// LDS layout per staged t: row r = c*2+plane (c 0..15), rows 32/33 = x re/im;
// wave w stages ts=w: instr c writes rows (2c,2c+1) = 64 lanes contiguous.
// Reads rt[row*32+fl] / rt[row*32+32+fl] merge to ds_read2_b32, bank = fl
// -> 2 lanes/bank over wave64 = conflict-free.
// ---------------------------------------------------------------------------
template<int TCH>
__global__ __launch_bounds__(320) void k1_cov(const float* __restrict__ mix,
                                              const float* __restrict__ tgt,
                                              float2* __restrict__ phi_pf,
                                              float2* __restrict__ syx_pf,
                                              float2* __restrict__ sy_pf,
                                              float2* __restrict__ sx_pf) {
  __shared__ float ys[2 * SBUF_];
  v2f* phi_p = (v2f*)phi_pf;
  v2f* syx_p = (v2f*)syx_pf;
  v2f* sy_p  = (v2f*)sy_pf;
  v2f* sx_p  = (v2f*)sx_pf;
  const int tid = threadIdx.x;
  const int ft = blockIdx.x, tc = blockIdx.y, n = blockIdx.z;
  const int fbase = ft * FT_;
  const int t0 = tc * TCH;
  const int fl = tid & 31;
  const int g  = tid >> 5;          // 0..9
  int ti = 0, tj = g;               // lower-triangle tile decode, ti>=tj
  while (tj > ti) { ++ti; tj -= ti; }
  const int c0 = ti * 4;
  const int d0 = tj * 4;
  const bool sThread = (tj == 0);   // tiles (0..3,0): c0 covers 0,4,8,12

  // staging decode: wave w stages ts=w; lane = plane*32 + fl
  const int w     = tid >> 6;           // 0..4 (uniform per wave)
  const int plane = (tid >> 5) & 1;     // 0 = re, 1 = im
  const int f_ld  = min(fbase + fl, F_ - 1);   // clamped OOB f

  const float* mixN = mix + n * N2CTF_;
  const float* tgtN = tgt + n * N2CTF_;
  const float* ysrc = mixN + plane * CTF_ + (t0 + w) * F_ + f_ld;  // c=0, s=0
  const float* xsrc = tgtN + plane * CTF_ + (t0 + w) * F_ + f_ld;  // ref mic

  v2f acc[4][4];
  #pragma unroll
  for (int i = 0; i < 4; ++i)
    #pragma unroll
    for (int j = 0; j < 4; ++j) acc[i][j] = (v2f){0.f, 0.f};
  v2f syx[4], sy[4], sx = (v2f){0.f, 0.f};
  #pragma unroll
  for (int i = 0; i < 4; ++i) { syx[i] = (v2f){0.f,0.f}; sy[i] = (v2f){0.f,0.f}; }

  constexpr int NS = TCH / TS_;

  // prologue: issue stage-0 DMA into buffer 0
  {
    float* dst = &ys[w * SSTG_];
    #pragma unroll
    for (int c = 0; c < 16; ++c) gload4(ysrc + c * TF_, dst + 2 * c * 32);
    gload4(xsrc, dst + 32 * 32);
  }

  for (int s = 0; s < NS; ++s) {
    __syncthreads();                 // vmcnt(0)+barrier: buf[s&1] ready everywhere
    if (s + 1 < NS) {                // issue next-stage DMA (drains at next barrier)
      float* dst = &ys[((s + 1) & 1) * SBUF_ + w * SSTG_];
      const float* yp = ysrc + (s + 1) * (TS_ * F_);
      #pragma unroll
      for (int c = 0; c < 16; ++c) gload4(yp + c * TF_, dst + 2 * c * 32);
      gload4(xsrc + (s + 1) * (TS_ * F_), dst + 32 * 32);
    }
    const float* bufc = &ys[(s & 1) * SBUF_];
    #pragma unroll
    for (int tl = 0; tl < TS_; ++tl) {
      const float* rt = bufc + tl * SSTG_;
      v2f a[4], bu[4], bv[4];
      #pragma unroll
      for (int i = 0; i < 4; ++i) {
        float re = rt[(2 * (c0 + i)) * 32 + fl];
        float im = rt[(2 * (c0 + i)) * 32 + 32 + fl];
        a[i] = (v2f){re, im};
      }
      #pragma unroll
      for (int j = 0; j < 4; ++j) {
        float re = rt[(2 * (d0 + j)) * 32 + fl];
        float im = rt[(2 * (d0 + j)) * 32 + 32 + fl];
        bu[j] = (v2f){re, -im};            // for y_c * conj(y_d)
        bv[j] = (v2f){im,  re};
      }
      #pragma unroll
      for (int i = 0; i < 4; ++i)
        #pragma unroll
        for (int j = 0; j < 4; ++j)
          acc[i][j] += a[i].x * bu[j] + a[i].y * bv[j];
      if (sThread) {
        float xre = rt[32 * 32 + fl];
        float xim = rt[33 * 32 + fl];
        v2f xu = (v2f){xre, -xim};
        v2f xw = (v2f){xim,  xre};
        #pragma unroll
        for (int i = 0; i < 4; ++i) {
          syx[i] += a[i].x * xu + a[i].y * xw;   // y_c * conj(x0)
          sy[i]  += a[i];
        }
        if (g == 0) sx += (v2f){xre, xim};
      }
    }
  }

  const int f = fbase + fl;
  if (f < F_) {
    const int tcn = tc * N_ + n;
    // tile g stored at offset g*16, row-major 4x4 -> 128 B contiguous/lane
    v2f* pb = phi_p + ((size_t)tcn * F_ + f) * PHIC_ + g * 16;
    #pragma unroll
    for (int i = 0; i < 4; ++i)
      #pragma unroll
      for (int j = 0; j < 4; ++j) pb[i * 4 + j] = acc[i][j];
    if (sThread) {
      v2f* s1 = syx_p + ((size_t)tcn * F_ + f) * C_ + c0;
      v2f* s2 = sy_p  + ((size_t)tcn * F_ + f) * C_ + c0;
      #pragma unroll
      for (int i = 0; i < 4; ++i) { s1[i] = syx[i]; s2[i] = sy[i]; }
      if (g == 0) sx_p[(size_t)tcn * F_ + f] = sx;
    }
  }
}

// ---------------------------------------------------------------------------
// K2a: streaming reduction. grid (F_, N_), block 256 = (i,j) of 16x16 M.
// Upper triangle reconstructed from conj of stored lower tiles. Builds M
// (+diag load) and rhs, writes packed 272-float2 record per (n,f).
// ---------------------------------------------------------------------------
template<int TCP>
__global__ __launch_bounds__(256) void k2a_reduce(const float2* __restrict__ phi_p,
                                                  const float2* __restrict__ syx_p,
                                                  const float2* __restrict__ sy_p,
                                                  const float2* __restrict__ sx_p,
                                                  float2* __restrict__ Mg) {
  __shared__ float2 ld_sy[TCP * N_ * C_];
  __shared__ float2 ld_syx[TCP * C_];
  __shared__ float2 ld_sx[TCP * N_];
  __shared__ float2 muB_s, sxO_s;
  const int f = blockIdx.x, n = blockIdx.y;
  const int tid = threadIdx.x;
  const int i = tid >> 4, j = tid & 15;

  // Hermitian mirror: (i,j) in lower tile (ti,tj) directly, else conj (j,i).
  const int ti = i >> 2, tj = j >> 2, ci = i & 3, cj = j & 3;
  int gL, cell; bool cj_flip;
  if (ti >= tj) { gL = ti * (ti + 1) / 2 + tj; cell = ci * 4 + cj; cj_flip = false; }
  else          { gL = tj * (tj + 1) / 2 + ti; cell = cj * 4 + ci; cj_flip = true; }
  const int off = gL * 16 + cell;

  float2 s = make_float2(0.f, 0.f);
  for (int tc = 0; tc < TCP; ++tc) {
    float2 v = phi_p[((size_t)(tc * N_ + n) * F_ + f) * PHIC_ + off];
    s.x += v.x; s.y += v.y;
  }
  if (cj_flip) s.y = -s.y;
  if (i == j) { s.x += (float)T_ * LOADC; s.y += (float)T_ * LOADC; }

  for (int idx = tid; idx < TCP * N_ * C_; idx += 256) {
    int tcn = idx >> 4, c = idx & 15;
    ld_sy[idx] = sy_p[((size_t)tcn * F_ + f) * C_ + c];
  }
  for (int idx = tid; idx < TCP * C_; idx += 256) {
    int tc = idx >> 4, c = idx & 15;
    ld_syx[idx] = syx_p[((size_t)(tc * N_ + n) * F_ + f) * C_ + c];
  }
  for (int idx = tid; idx < TCP * N_; idx += 256) {
    ld_sx[idx] = sx_p[(size_t)idx * F_ + f];
  }
  __syncthreads();   // uniform

  float2 muA_r = make_float2(0.f,0.f), ownY = make_float2(0.f,0.f), ownYX = make_float2(0.f,0.f);
  if (tid < 16) {
    float2 allY = make_float2(0.f,0.f);
    for (int tcn = 0; tcn < TCP * N_; ++tcn) allY = cadd(allY, ld_sy[tcn * C_ + tid]);
    for (int tc = 0; tc < TCP; ++tc) {
      ownY  = cadd(ownY,  ld_sy[(tc * N_ + n) * C_ + tid]);
      ownYX = cadd(ownYX, ld_syx[tc * C_ + tid]);
    }
    const float invNT = 1.0f / ((float)N_ * (float)T_);
    muA_r = make_float2(allY.x * invNT, allY.y * invNT);
  }
  if (tid == 16) {
    float2 own = make_float2(0.f,0.f), all = make_float2(0.f,0.f);
    for (int tc = 0; tc < TCP; ++tc)
      for (int nn = 0; nn < N_; ++nn) {
        float2 v = ld_sx[tc * N_ + nn];
        all = cadd(all, v);
        if (nn == n) own = cadd(own, v);
      }
    const float invNT = 1.0f / ((float)N_ * (float)T_);
    muB_s = make_float2(all.x * invNT, all.y * invNT);
    sxO_s = own;
  }
  __syncthreads();   // uniform: publish muB_s/sxO_s

  float2* dst = Mg + (size_t)(n * F_ + f) * MREC_;
  dst[tid] = s;                          // coalesced 2 KB store
  if (tid < 16) {
    // rhs = S_yx - muA*conj(S_x_own) - conj(muB)*S_y_own + T*muA*conj(muB)
    float2 r = ownYX;
    r = csub(r, cmulc(muA_r, sxO_s));
    r = csub(r, cmulc(ownY, muB_s));
    float2 t3 = cmulc(muA_r, muB_s);
    r.x += (float)T_ * t3.x; r.y += (float)T_ * t3.y;
    dst[256 + tid] = r;
  }
}

// ---------------------------------------------------------------------------
// K2b: Gauss-Jordan solve, one wave per (n,f) (barriers ~free single-wave).
// No pivoting (diag-dominant). Unchanged (passed R5/R6).
// ---------------------------------------------------------------------------
__global__ __launch_bounds__(64) void k2b_solve(const float2* __restrict__ Mg,
                                                float* __restrict__ wre,
                                                float* __restrict__ wim) {
  __shared__ float2 M[16 * 17];
  const int f = blockIdx.x, n = blockIdx.y;
  const int tid = threadIdx.x;
  const float2* src = Mg + (size_t)(n * F_ + f) * MREC_;
  #pragma unroll
  for (int r = 0; r < 4; ++r) {
    int idx = tid + 64 * r;
    M[(idx >> 4) * 17 + (idx & 15)] = src[idx];
  }
  if (tid < 16) M[tid * 17 + 16] = src[256 + tid];
  __syncthreads();

  const int i = tid >> 2, q = tid & 3;
  for (int k = 0; k < 16; ++k) {
    float2 fac = cdiv(M[i * 17 + k], M[k * 17 + k]);
    __syncthreads();
    if (i != k) {
      #pragma unroll
      for (int jj = 0; jj < 4; ++jj) {
        int j = q * 4 + jj;
        M[i * 17 + j] = csub(M[i * 17 + j], cmul(fac, M[k * 17 + j]));
      }
      if (q == 3) M[i * 17 + 16] = csub(M[i * 17 + 16], cmul(fac, M[k * 17 + 16]));
    }
    __syncthreads();
  }
  if (q == 0) {
    float2 w = cdiv(M[i * 17 + 16], M[i * 17 + i]);
    wre[(n * C_ + i) * F_ + f] = w.x;
    wim[(n * C_ + i) * F_ + f] = w.y;
  }
}

// ---------------------------------------------------------------------------
// K3 v5: beamform, 2 t's per block. grid (T_/2, N_) = 1200 blocks x 320 thr
// (5 waves) = 23 waves/CU. f = tid single-pass.
// ---------------------------------------------------------------------------
__global__ __launch_bounds__(320) void k3_bf(const float* __restrict__ mix,
                                             const float* __restrict__ wre,
                                             const float* __restrict__ wim,
                                             float* __restrict__ out) {
  const int t0 = blockIdx.x * 2, n = blockIdx.y;
  const int f = threadIdx.x;
  if (f >= F_) return;
  const float* mixN = mix + n * N2CTF_;
  const float* wR = wre + n * C_ * F_;
  const float* wI = wim + n * C_ * F_;
  float* outN = out + n * 2 * TF_;
  float wr[16], wi[16];
  #pragma unroll
  for (int c = 0; c < 16; ++c) { wr[c] = wR[c * F_ + f]; wi[c] = wI[c * F_ + f]; }
  const float* yb = mixN + t0 * F_ + f;
  float xr0 = 0.f, xi0 = 0.f, xr1 = 0.f, xi1 = 0.f;
  #pragma unroll
  for (int c = 0; c < 16; ++c) {
    float yr0 = yb[c * TF_],      yi0 = yb[CTF_ + c * TF_];
    float yr1 = yb[c * TF_ + F_], yi1 = yb[CTF_ + c * TF_ + F_];
    xr0 += wr[c] * yr0 + wi[c] * yi0;   // conj(w)*y
    xi0 += wr[c] * yi0 - wi[c] * yr0;
    xr1 += wr[c] * yr1 + wi[c] * yi1;
    xi1 += wr[c] * yi1 - wi[c] * yr1;
  }
  outN[t0 * F_ + f] = xr0;
  outN[TF_ + t0 * F_ + f] = xi0;
  outN[(t0 + 1) * F_ + f] = xr1;
  outN[TF_ + (t0 + 1) * F_ + f] = xi1;
}

// ---------------------------------------------------------------------------
template<int TCP>
static void launch_all(const float* mix, const float* tgt, float* ws, float* out,
                       hipStream_t stream) {
  constexpr int TCH = T_ / TCP;
  static_assert(TCH * TCP == T_ && TCH % TS_ == 0, "chunking");
  float2* phi_p = (float2*)ws;
  float2* syx_p = phi_p + (size_t)TCP * N_ * F_ * PHIC_;
  float2* sy_p  = syx_p + (size_t)TCP * N_ * F_ * C_;
  float2* sx_p  = sy_p  + (size_t)TCP * N_ * F_ * C_;
  float2* Mg    = sx_p  + (size_t)TCP * N_ * F_;
  float*  wre   = (float*)(Mg + (size_t)N_ * F_ * MREC_);
  float*  wim   = wre + N_ * C_ * F_;
  k1_cov<TCH><<<dim3(NFT_, TCP, N_), dim3(320), 0, stream>>>(mix, tgt, phi_p, syx_p, sy_p, sx_p);
  k2a_reduce<TCP><<<dim3(F_, N_), dim3(256), 0, stream>>>(phi_p, syx_p, sy_p, sx_p, Mg);
  k2b_solve<<<dim3(F_, N_), dim3(64), 0, stream>>>(Mg, wre, wim);
  k3_bf<<<dim3(T_ / 2, N_), dim3(320), 0, stream>>>(mix, wre, wim, out);
}

static size_t ws_need_bytes(int tcp) {
  size_t fl2 = (size_t)tcp * N_ * F_ * (PHIC_ + C_ + C_ + 1) + (size_t)N_ * F_ * MREC_;
  return fl2 * 8 + 2ull * N_ * C_ * F_ * 4;
}

extern "C" void kernel_launch(void* const* d_in, const int* in_sizes, int n_in,
                              void* d_out, int out_size, void* d_ws, size_t ws_size,
                              hipStream_t stream) {
  const float* mix = (const float*)d_in[0];
  const float* tgt = (const float*)d_in[1];
  // d_in[2] (steering_vector) is unused by the reference.
  float* out = (float*)d_out;
  float* ws  = (float*)d_ws;
  if (ws_size >= ws_need_bytes(10))      launch_all<10>(mix, tgt, ws, out, stream);
  else if (ws_size >= ws_need_bytes(6))  launch_all<6>(mix, tgt, ws, out, stream);
  else if (ws_size >= ws_need_bytes(2))  launch_all<2>(mix, tgt, ws, out, stream);
  else                                   launch_all<1>(mix, tgt, ws, out, stream);
}